// Round 1
// baseline (1309.410 us; speedup 1.0000x reference)
//
#include <hip/hip_runtime.h>
#include <math.h>

#define DIM 256
#define RB 64   // rows per block (kernel 2)
#define CB 64   // codebook cols per tile (kernel 2)

__device__ __forceinline__ float waveReduceSum(float v) {
#pragma unroll
    for (int off = 32; off >= 1; off >>= 1)
        v += __shfl_xor(v, off, 64);
    return v;
}

// ---------------- Kernel 1: en = l2norm(embed) rows ----------------
__global__ __launch_bounds__(256) void k_norm_rows(const float* __restrict__ in,
                                                   float* __restrict__ out, int K) {
    const int wave = threadIdx.x >> 6;
    const int lane = threadIdx.x & 63;
    const int row = blockIdx.x * 4 + wave;
    if (row >= K) return;
    const float4 v = *(const float4*)&in[(size_t)row * DIM + lane * 4];
    float ss = waveReduceSum(v.x * v.x + v.y * v.y + v.z * v.z + v.w * v.w);
    const float n = fmaxf(sqrtf(ss), 1e-12f);
    float4 o;
    o.x = v.x / n; o.y = v.y / n; o.z = v.z / n; o.w = v.w / n;
    *(float4*)&out[(size_t)row * DIM + lane * 4] = o;
}

// ---------------- Kernel 2: fused dist + argmax + gather + scatter ----------------
__global__ __launch_bounds__(256) void k_dist_argmax(
    const float* __restrict__ x, const float* __restrict__ embed,
    const float* __restrict__ en, float* __restrict__ quantize,
    float* __restrict__ ind_out, float* __restrict__ embed_sum,
    float* __restrict__ bins, int K)
{
    __shared__ float fn_t[DIM][RB];   // 64 KB, [j][r], fn transposed
    __shared__ float en_t[DIM][CB];   // 64 KB, [j][c], en tile transposed
    __shared__ float norms[RB];       // sumsq, then clamped norm
    __shared__ float redv[RB][16];
    __shared__ int   redi[RB][16];
    __shared__ int   fidx[RB];

    const int t = threadIdx.x;
    const int rbase = blockIdx.x * RB;
    const int rg = t & 15;   // row group: rows rg*4 .. rg*4+3
    const int jg = t >> 4;   // 0..15: j-chunk in staging, col group in compute

    if (t < RB) norms[t] = 0.0f;
    __syncthreads();

    // ---- stage fn (transposed) + row norms ----
    float4 xa[4][4];               // [row i][j4 m]
    float psum[4] = {0.f, 0.f, 0.f, 0.f};
#pragma unroll
    for (int m = 0; m < 4; ++m) {
        const int j0 = jg * 16 + m * 4;
#pragma unroll
        for (int i = 0; i < 4; ++i) {
            float4 v = *(const float4*)&x[(size_t)(rbase + rg * 4 + i) * DIM + j0];
            xa[i][m] = v;
            psum[i] += v.x * v.x + v.y * v.y + v.z * v.z + v.w * v.w;
        }
    }
#pragma unroll
    for (int i = 0; i < 4; ++i) atomicAdd(&norms[rg * 4 + i], psum[i]);
    __syncthreads();
    float nr[4];
#pragma unroll
    for (int i = 0; i < 4; ++i) nr[i] = fmaxf(sqrtf(norms[rg * 4 + i]), 1e-12f);
    __syncthreads();
    if (jg == 0) {
#pragma unroll
        for (int i = 0; i < 4; ++i) norms[rg * 4 + i] = nr[i];  // keep for scatter
    }
#pragma unroll
    for (int m = 0; m < 4; ++m) {
        const int j0 = jg * 16 + m * 4;
#pragma unroll
        for (int l = 0; l < 4; ++l) {
            float4 w;
            w.x = ((const float*)&xa[0][m])[l] / nr[0];
            w.y = ((const float*)&xa[1][m])[l] / nr[1];
            w.z = ((const float*)&xa[2][m])[l] / nr[2];
            w.w = ((const float*)&xa[3][m])[l] / nr[3];
            *(float4*)&fn_t[j0 + l][rg * 4] = w;
        }
    }

    float bestv[4] = {-2.f, -2.f, -2.f, -2.f};
    int besti[4] = {0, 0, 0, 0};

    for (int kt = 0; kt < K; kt += CB) {
        __syncthreads();   // previous tile's compute done (also covers fn_t on iter 0)
        // ---- stage en tile (transposed) ----
#pragma unroll
        for (int m = 0; m < 4; ++m) {
            const int j0 = jg * 16 + m * 4;
            float4 v0 = *(const float4*)&en[(size_t)(kt + rg * 4 + 0) * DIM + j0];
            float4 v1 = *(const float4*)&en[(size_t)(kt + rg * 4 + 1) * DIM + j0];
            float4 v2 = *(const float4*)&en[(size_t)(kt + rg * 4 + 2) * DIM + j0];
            float4 v3 = *(const float4*)&en[(size_t)(kt + rg * 4 + 3) * DIM + j0];
#pragma unroll
            for (int l = 0; l < 4; ++l) {
                float4 w;
                w.x = ((const float*)&v0)[l];
                w.y = ((const float*)&v1)[l];
                w.z = ((const float*)&v2)[l];
                w.w = ((const float*)&v3)[l];
                *(float4*)&en_t[j0 + l][rg * 4] = w;
            }
        }
        __syncthreads();

        // ---- 4x4 register tile, 4-way split accumulators ----
        float4 accp[4][4];
#pragma unroll
        for (int i = 0; i < 4; ++i)
#pragma unroll
            for (int l = 0; l < 4; ++l)
                accp[i][l] = make_float4(0.f, 0.f, 0.f, 0.f);

#pragma unroll 2
        for (int j4 = 0; j4 < DIM; j4 += 4) {
            float4 fv[4], ev[4];
#pragma unroll
            for (int c = 0; c < 4; ++c) {
                fv[c] = *(const float4*)&fn_t[j4 + c][rg * 4];
                ev[c] = *(const float4*)&en_t[j4 + c][jg * 4];
            }
#pragma unroll
            for (int c = 0; c < 4; ++c) {
#pragma unroll
                for (int i = 0; i < 4; ++i) {
                    const float f = ((const float*)&fv[c])[i];
#pragma unroll
                    for (int l = 0; l < 4; ++l)
                        ((float*)&accp[i][l])[c] += f * ((const float*)&ev[c])[l];
                }
            }
        }
#pragma unroll
        for (int i = 0; i < 4; ++i) {
#pragma unroll
            for (int l = 0; l < 4; ++l) {
                float4 a = accp[i][l];
                float v = (a.x + a.y) + (a.z + a.w);
                const int kk = kt + jg * 4 + l;
                if (v > bestv[i]) { bestv[i] = v; besti[i] = kk; }  // strict >: first-max wins
            }
        }
    }

    __syncthreads();
#pragma unroll
    for (int i = 0; i < 4; ++i) {
        redv[rg * 4 + i][jg] = bestv[i];
        redi[rg * 4 + i][jg] = besti[i];
    }
    __syncthreads();
    if (t < RB) {
        float bv = -3.f; int bi = 0x7fffffff;
        for (int g = 0; g < 16; ++g) {
            const float v = redv[t][g];
            const int idx = redi[t][g];
            if (v > bv || (v == bv && idx < bi)) { bv = v; bi = idx; }
        }
        fidx[t] = bi;
        ind_out[rbase + t] = (float)bi;
        atomicAdd(&bins[bi], 1.0f);
    }
    __syncthreads();

    // ---- gather quantize + scatter embed_sum ----
    for (int f = t; f < RB * (DIM / 4); f += 256) {
        const int r = f >> 6;
        const int j4 = (f & 63) * 4;
        const int idx = fidx[r];
        float4 e = *(const float4*)&embed[(size_t)idx * DIM + j4];
        *(float4*)&quantize[(size_t)(rbase + r) * DIM + j4] = e;
        float4 xv = *(const float4*)&x[(size_t)(rbase + r) * DIM + j4];
        const float n = norms[r];
        atomicAdd(&embed_sum[(size_t)idx * DIM + j4 + 0], xv.x / n);
        atomicAdd(&embed_sum[(size_t)idx * DIM + j4 + 1], xv.y / n);
        atomicAdd(&embed_sum[(size_t)idx * DIM + j4 + 2], xv.z / n);
        atomicAdd(&embed_sum[(size_t)idx * DIM + j4 + 3], xv.w / n);
    }
}

// ---------------- Kernel 3: EMA update ----------------
__global__ __launch_bounds__(256) void k_update(const float* __restrict__ embed,
    const float* __restrict__ en, const float* __restrict__ embed_sum,
    const float* __restrict__ bins, float* __restrict__ embed_new, int K)
{
    const int wave = threadIdx.x >> 6;
    const int lane = threadIdx.x & 63;
    const int k = blockIdx.x * 4 + wave;
    if (k >= K) return;
    const float b = bins[k];
    const float bs = (b == 0.f) ? 1.f : b;
    float4 s = *(const float4*)&embed_sum[(size_t)k * DIM + lane * 4];
    float4 v;
    v.x = s.x / bs; v.y = s.y / bs; v.z = s.z / bs; v.w = s.w / bs;
    float ss = waveReduceSum(v.x * v.x + v.y * v.y + v.z * v.z + v.w * v.w);
    const float n = fmaxf(sqrtf(ss), 1e-12f);
    float4 nv;
    nv.x = v.x / n; nv.y = v.y / n; nv.z = v.z / n; nv.w = v.w / n;
    if (b == 0.f) nv = *(const float4*)&en[(size_t)k * DIM + lane * 4];
    float4 e = *(const float4*)&embed[(size_t)k * DIM + lane * 4];
    float4 o;
    o.x = 0.8f * e.x + 0.2f * nv.x;
    o.y = 0.8f * e.y + 0.2f * nv.y;
    o.z = 0.8f * e.z + 0.2f * nv.z;
    o.w = 0.8f * e.w + 0.2f * nv.w;
    *(float4*)&embed_new[(size_t)k * DIM + lane * 4] = o;
}

extern "C" void kernel_launch(void* const* d_in, const int* in_sizes, int n_in,
                              void* d_out, int out_size, void* d_ws, size_t ws_size,
                              hipStream_t stream) {
    const float* x = (const float*)d_in[0];
    const float* embed = (const float*)d_in[1];
    const int N = in_sizes[0] / DIM;   // 16384
    const int K = in_sizes[1] / DIM;   // 8192

    float* quantize  = (float*)d_out;
    float* ind_out   = quantize + (size_t)N * DIM;
    float* embed_new = ind_out + N;

    float* en        = (float*)d_ws;                 // K*DIM
    float* embed_sum = en + (size_t)K * DIM;         // K*DIM
    float* bins      = embed_sum + (size_t)K * DIM;  // K

    // zero scatter targets every call (ws is poisoned once, never re-zeroed)
    hipMemsetAsync(embed_sum, 0, ((size_t)K * DIM + K) * sizeof(float), stream);

    k_norm_rows<<<(K + 3) / 4, 256, 0, stream>>>(embed, en, K);
    k_dist_argmax<<<N / RB, 256, 0, stream>>>(x, embed, en, quantize, ind_out,
                                              embed_sum, bins, K);
    k_update<<<(K + 3) / 4, 256, 0, stream>>>(embed, en, embed_sum, bins, embed_new, K);
}

// Round 3
// 490.593 us; speedup vs baseline: 2.6690x; 2.6690x over previous
//
#include <hip/hip_runtime.h>
#include <math.h>

#define DIM 256
#define NROWS_TILE 128
#define CB 128
#define SPLITS 8
#define NCAND (SPLITS * 2)         // per-(split, wc) candidate slots
#define CODES_PER_SPLIT 1024       // K / SPLITS, K = 8192

typedef __attribute__((ext_vector_type(8))) _Float16 f16x8;
typedef __attribute__((ext_vector_type(4))) _Float16 f16x4;
typedef __attribute__((ext_vector_type(4))) float f32x4;

__device__ __forceinline__ float waveReduceSum(float v) {
#pragma unroll
    for (int off = 32; off >= 1; off >>= 1) v += __shfl_xor(v, off, 64);
    return v;
}

// ---------- prep: row-l2norm + split-f16 encode (hi + lo*2048) ----------
__global__ __launch_bounds__(256) void k_prep(const float* __restrict__ in,
        _Float16* __restrict__ hi, _Float16* __restrict__ lo,
        float* __restrict__ norms, int nrows)
{
    const int w = threadIdx.x >> 6, lane = threadIdx.x & 63;
    const int r = blockIdx.x * 4 + w;
    if (r >= nrows) return;
    f32x4 v = *(const f32x4*)&in[(size_t)r * DIM + lane * 4];
    float ss = waveReduceSum(v[0]*v[0] + v[1]*v[1] + v[2]*v[2] + v[3]*v[3]);
    const float n = fmaxf(sqrtf(ss), 1e-12f);
    if (norms != nullptr && lane == 0) norms[r] = n;
    f32x4 f;
    f[0] = v[0] / n; f[1] = v[1] / n; f[2] = v[2] / n; f[3] = v[3] / n;
    f16x4 h, l;
#pragma unroll
    for (int c = 0; c < 4; ++c) {
        h[c] = (_Float16)f[c];
        l[c] = (_Float16)((f[c] - (float)h[c]) * 2048.0f);
    }
    *(f16x4*)&hi[(size_t)r * DIM + lane * 4] = h;
    *(f16x4*)&lo[(size_t)r * DIM + lane * 4] = l;
}

// ---------- main: split-f16 MFMA GEMM-BT + fused row argmax ----------
// grid: (N/128 row tiles, SPLITS). Block 256 thr = 4 waves (2x2 of 64x64).
__global__ __launch_bounds__(256, 2) void k_gemm(
    const _Float16* __restrict__ fnh, const _Float16* __restrict__ fnl,
    const _Float16* __restrict__ enh, const _Float16* __restrict__ enl,
    float* __restrict__ cand_val, int* __restrict__ cand_idx)
{
    // fragment-native layout: 16 frags x 1KB per array; frag = [rb(8)][kf(2)],
    // within frag: lane*16B holds 8 contiguous k of row (lane&15), k-off (lane>>4)*8.
    __shared__ _Float16 smem[32768];   // 64 KB
    _Float16* const lAh = smem;
    _Float16* const lAl = smem + 8192;
    _Float16* const lBh = smem + 16384;
    _Float16* const lBl = smem + 24576;

    const int t = threadIdx.x;
    const int w = t >> 6, lane = t & 63;
    const int wr = w >> 1, wc = w & 1;
    const int rbase = blockIdx.x * NROWS_TILE;
    const int cbase = blockIdx.y * CODES_PER_SPLIT;

    // wave w stages one array
    const _Float16* const src = (w == 0) ? fnh : (w == 1) ? fnl : (w == 2) ? enh : enl;
    _Float16* const dst = (w == 0) ? lAh : (w == 1) ? lAl : (w == 2) ? lBh : lBl;

    float bestv[4][4];
    int   besti[4][4];
#pragma unroll
    for (int i = 0; i < 4; ++i)
#pragma unroll
        for (int rg = 0; rg < 4; ++rg) { bestv[i][rg] = -2.0f; besti[i][rg] = 0; }

#pragma unroll 1
    for (int tile = 0; tile < CODES_PER_SPLIT / CB; ++tile) {
        const int cb = cbase + tile * CB;
        const int rowb = (w < 2) ? rbase : cb;

        f32x4 acc0[4][4], acc1[4][4];
#pragma unroll
        for (int i = 0; i < 4; ++i)
#pragma unroll
            for (int j = 0; j < 4; ++j) {
                acc0[i][j] = (f32x4){0.f, 0.f, 0.f, 0.f};
                acc1[i][j] = (f32x4){0.f, 0.f, 0.f, 0.f};
            }

#pragma unroll 1
        for (int kk = 0; kk < DIM; kk += 64) {
            // stage 16 KB per wave into fragment-native slots
#pragma unroll
            for (int q = 0; q < 16; ++q) {
                const _Float16* g = src + (size_t)(rowb + (q >> 1) * 16 + (lane & 15)) * DIM
                                        + kk + (q & 1) * 32 + (lane >> 4) * 8;
                *(int4*)(dst + q * 512 + lane * 8) = *(const int4*)g;
            }
            __syncthreads();
#pragma unroll
            for (int kf = 0; kf < 2; ++kf) {
                f16x8 Ah[4], Al[4];
#pragma unroll
                for (int i = 0; i < 4; ++i) {
                    const int fi = ((wr * 4 + i) * 2 + kf) * 512 + lane * 8;
                    Ah[i] = *(const f16x8*)(lAh + fi);
                    Al[i] = *(const f16x8*)(lAl + fi);
                }
#pragma unroll
                for (int j = 0; j < 4; ++j) {
                    const int fj = ((wc * 4 + j) * 2 + kf) * 512 + lane * 8;
                    f16x8 Bh = *(const f16x8*)(lBh + fj);
                    f16x8 Bl = *(const f16x8*)(lBl + fj);
#pragma unroll
                    for (int i = 0; i < 4; ++i) {
                        acc0[i][j] = __builtin_amdgcn_mfma_f32_16x16x32_f16(Ah[i], Bh, acc0[i][j], 0, 0, 0);
                        acc1[i][j] = __builtin_amdgcn_mfma_f32_16x16x32_f16(Ah[i], Bl, acc1[i][j], 0, 0, 0);
                        acc1[i][j] = __builtin_amdgcn_mfma_f32_16x16x32_f16(Al[i], Bh, acc1[i][j], 0, 0, 0);
                    }
                }
            }
            __syncthreads();
        }

        // epilogue: combine, reduce over 16 cols (j in-register, then lane butterfly)
#pragma unroll
        for (int i = 0; i < 4; ++i) {
#pragma unroll
            for (int rg = 0; rg < 4; ++rg) {
                float bv = -3e30f; int bix = 0;
#pragma unroll
                for (int j = 0; j < 4; ++j) {
                    const float vv = acc0[i][j][rg] + acc1[i][j][rg] * (1.0f / 2048.0f);
                    const int ii = cb + wc * 64 + j * 16 + (lane & 15);
                    if (vv > bv) { bv = vv; bix = ii; }
                }
#pragma unroll
                for (int off = 1; off < 16; off <<= 1) {
                    const float ov = __shfl_xor(bv, off, 16);
                    const int oi = __shfl_xor(bix, off, 16);
                    if (ov > bv || (ov == bv && oi < bix)) { bv = ov; bix = oi; }
                }
                if (bv > bestv[i][rg]) { bestv[i][rg] = bv; besti[i][rg] = bix; }
            }
        }
    }

    // one private slot per (row, split, wc): no cross-wave race
    if ((lane & 15) == 0) {
#pragma unroll
        for (int i = 0; i < 4; ++i)
#pragma unroll
            for (int rg = 0; rg < 4; ++rg) {
                const int r = rbase + wr * 64 + i * 16 + (lane >> 4) * 4 + rg;
                cand_val[(size_t)r * NCAND + blockIdx.y * 2 + wc] = bestv[i][rg];
                cand_idx[(size_t)r * NCAND + blockIdx.y * 2 + wc] = besti[i][rg];
            }
    }
}

// ---------- merge splits + gather quantize + scatter embed_sum ----------
__global__ __launch_bounds__(256) void k_merge(
    const float* __restrict__ x, const float* __restrict__ embed,
    const float* __restrict__ cand_val, const int* __restrict__ cand_idx,
    const float* __restrict__ xnorm,
    float* __restrict__ quantize, float* __restrict__ ind_out,
    float* __restrict__ embed_sum, float* __restrict__ bins)
{
    const int w = threadIdx.x >> 6, lane = threadIdx.x & 63;
    const int r = blockIdx.x * 4 + w;
    float v = -3e30f; int ix = 0x7fffffff;
    if (lane < NCAND) {
        v = cand_val[(size_t)r * NCAND + lane];
        ix = cand_idx[(size_t)r * NCAND + lane];
    }
#pragma unroll
    for (int off = 1; off < 16; off <<= 1) {
        const float ov = __shfl_xor(v, off, 16);
        const int oi = __shfl_xor(ix, off, 16);
        if (ov > v || (ov == v && oi < ix)) { v = ov; ix = oi; }
    }
    ix = __shfl(ix, 0, 64);
    if (lane == 0) {
        ind_out[r] = (float)ix;
        atomicAdd(&bins[ix], 1.0f);
    }
    f32x4 e = *(const f32x4*)&embed[(size_t)ix * DIM + lane * 4];
    *(f32x4*)&quantize[(size_t)r * DIM + lane * 4] = e;
    f32x4 xv = *(const f32x4*)&x[(size_t)r * DIM + lane * 4];
    const float n = xnorm[r];
    atomicAdd(&embed_sum[(size_t)ix * DIM + lane * 4 + 0], xv[0] / n);
    atomicAdd(&embed_sum[(size_t)ix * DIM + lane * 4 + 1], xv[1] / n);
    atomicAdd(&embed_sum[(size_t)ix * DIM + lane * 4 + 2], xv[2] / n);
    atomicAdd(&embed_sum[(size_t)ix * DIM + lane * 4 + 3], xv[3] / n);
}

// ---------- EMA update (en recomputed inline) ----------
__global__ __launch_bounds__(256) void k_update(const float* __restrict__ embed,
    const float* __restrict__ embed_sum, const float* __restrict__ bins,
    float* __restrict__ embed_new, int K)
{
    const int w = threadIdx.x >> 6, lane = threadIdx.x & 63;
    const int k = blockIdx.x * 4 + w;
    if (k >= K) return;
    f32x4 e = *(const f32x4*)&embed[(size_t)k * DIM + lane * 4];
    float sse = waveReduceSum(e[0]*e[0] + e[1]*e[1] + e[2]*e[2] + e[3]*e[3]);
    const float ne = fmaxf(sqrtf(sse), 1e-12f);

    const float b = bins[k];
    const float bs = (b == 0.f) ? 1.f : b;
    f32x4 s = *(const f32x4*)&embed_sum[(size_t)k * DIM + lane * 4];
    f32x4 vv;
    vv[0] = s[0] / bs; vv[1] = s[1] / bs; vv[2] = s[2] / bs; vv[3] = s[3] / bs;
    float ssv = waveReduceSum(vv[0]*vv[0] + vv[1]*vv[1] + vv[2]*vv[2] + vv[3]*vv[3]);
    const float nv = fmaxf(sqrtf(ssv), 1e-12f);

    f32x4 o;
#pragma unroll
    for (int c = 0; c < 4; ++c) {
        const float norm_c = (b == 0.f) ? (e[c] / ne) : (vv[c] / nv);
        o[c] = 0.8f * e[c] + 0.2f * norm_c;
    }
    *(f32x4*)&embed_new[(size_t)k * DIM + lane * 4] = o;
}

extern "C" void kernel_launch(void* const* d_in, const int* in_sizes, int n_in,
                              void* d_out, int out_size, void* d_ws, size_t ws_size,
                              hipStream_t stream) {
    const float* x = (const float*)d_in[0];
    const float* embed = (const float*)d_in[1];
    const int N = in_sizes[0] / DIM;   // 16384
    const int K = in_sizes[1] / DIM;   // 8192

    float* quantize  = (float*)d_out;
    float* ind_out   = quantize + (size_t)N * DIM;
    float* embed_new = ind_out + N;

    char* ws = (char*)d_ws;
    _Float16* fnh = (_Float16*)ws;                               // [0, 8M)
    _Float16* fnl = (_Float16*)(ws + (size_t)N * DIM * 2);       // [8M, 16M)
    _Float16* enh = (_Float16*)(ws + (size_t)N * DIM * 4);       // [16M, 20M)
    _Float16* enl = (_Float16*)(ws + (size_t)N * DIM * 4 + (size_t)K * DIM * 2);
    char* p = ws + (size_t)N * DIM * 4 + (size_t)K * DIM * 4;    // 24M
    float* xnorm    = (float*)p;                 p += (size_t)N * 4;
    float* cand_val = (float*)p;                 p += (size_t)N * NCAND * 4;
    int*   cand_idx = (int*)p;
    // embed_sum/bins alias fnh/fnl (dead after k_gemm)
    float* embed_sum = (float*)ws;               // K*DIM floats = 8 MB
    float* bins      = embed_sum + (size_t)K * DIM;

    k_prep<<<(N + 3) / 4, 256, 0, stream>>>(x, fnh, fnl, xnorm, N);
    k_prep<<<(K + 3) / 4, 256, 0, stream>>>(embed, enh, enl, nullptr, K);

    dim3 grid(N / NROWS_TILE, SPLITS);
    k_gemm<<<grid, 256, 0, stream>>>(fnh, fnl, enh, enl, cand_val, cand_idx);

    hipMemsetAsync(embed_sum, 0, ((size_t)K * DIM + K) * sizeof(float), stream);

    k_merge<<<(N + 3) / 4, 256, 0, stream>>>(x, embed, cand_val, cand_idx, xnorm,
                                             quantize, ind_out, embed_sum, bins);
    k_update<<<(K + 3) / 4, 256, 0, stream>>>(embed, embed_sum, bins, embed_new, K);
}

// Round 4
// 383.413 us; speedup vs baseline: 3.4151x; 1.2795x over previous
//
#include <hip/hip_runtime.h>
#include <math.h>

#define DIM 256
#define NROWS_TILE 128
#define CB 128
#define SPLITS 8
#define NCAND (SPLITS * 2)         // per-(split, wc) candidate slots
#define CODES_PER_SPLIT 1024       // K / SPLITS, K = 8192
#define KCH 32                     // k per staged chunk
#define CPT (DIM / KCH)            // 8 chunks per tile
#define NTILES (CODES_PER_SPLIT / CB)   // 8
#define NCHUNKS (NTILES * CPT)     // 64

typedef __attribute__((ext_vector_type(8))) _Float16 f16x8;
typedef __attribute__((ext_vector_type(4))) _Float16 f16x4;
typedef __attribute__((ext_vector_type(4))) float f32x4;

__device__ __forceinline__ void gload16(const void* g, void* l) {
    __builtin_amdgcn_global_load_lds(
        (const __attribute__((address_space(1))) void*)g,
        (__attribute__((address_space(3))) void*)l, 16, 0, 0);
}

__device__ __forceinline__ float waveReduceSum(float v) {
#pragma unroll
    for (int off = 32; off >= 1; off >>= 1) v += __shfl_xor(v, off, 64);
    return v;
}

// ---------- prep: row-l2norm + split-f16 encode (hi + lo*2048) ----------
__global__ __launch_bounds__(256) void k_prep(const float* __restrict__ in,
        _Float16* __restrict__ hi, _Float16* __restrict__ lo,
        float* __restrict__ norms, int nrows)
{
    const int w = threadIdx.x >> 6, lane = threadIdx.x & 63;
    const int r = blockIdx.x * 4 + w;
    if (r >= nrows) return;
    f32x4 v = *(const f32x4*)&in[(size_t)r * DIM + lane * 4];
    float ss = waveReduceSum(v[0]*v[0] + v[1]*v[1] + v[2]*v[2] + v[3]*v[3]);
    const float n = fmaxf(sqrtf(ss), 1e-12f);
    if (norms != nullptr && lane == 0) norms[r] = n;
    f32x4 f;
    f[0] = v[0] / n; f[1] = v[1] / n; f[2] = v[2] / n; f[3] = v[3] / n;
    f16x4 h, l;
#pragma unroll
    for (int c = 0; c < 4; ++c) {
        h[c] = (_Float16)f[c];
        l[c] = (_Float16)((f[c] - (float)h[c]) * 2048.0f);
    }
    *(f16x4*)&hi[(size_t)r * DIM + lane * 4] = h;
    *(f16x4*)&lo[(size_t)r * DIM + lane * 4] = l;
}

// ---------- main: split-f16 MFMA GEMM-BT + fused row argmax ----------
// grid: (N/128 row tiles, SPLITS). Block 256 thr = 4 waves (2x2 of 64x64).
// Double-buffered K=32 chunks staged via global_load_lds; raw s_barrier with
// manual vmcnt(0) so next-chunk loads overlap current-chunk ds_read+MFMA.
__global__ __launch_bounds__(256, 2) void k_gemm(
    const _Float16* __restrict__ fnh, const _Float16* __restrict__ fnl,
    const _Float16* __restrict__ enh, const _Float16* __restrict__ enl,
    float* __restrict__ cand_val, int* __restrict__ cand_idx)
{
    // per buf: 4 arrays x 8 frags x 1KB. frag q = rows q*16..q*16+15 of the
    // array's 128-row panel, k-chunk 32. lane slot: row=lane&15, kgrp=lane>>4.
    __shared__ _Float16 smem[2][16384];   // 2 x 32 KB

    const int t = threadIdx.x;
    const int w = t >> 6, lane = t & 63;
    const int wr = w >> 1, wc = w & 1;
    const int rbase = blockIdx.x * NROWS_TILE;
    const int cbase = blockIdx.y * CODES_PER_SPLIT;

    // wave w stages one array per chunk
    const _Float16* const src = (w == 0) ? fnh : (w == 1) ? fnl : (w == 2) ? enh : enl;
    const bool isA = (w < 2);

    float bestv[4][4];
    int   besti[4][4];
#pragma unroll
    for (int i = 0; i < 4; ++i)
#pragma unroll
        for (int rg = 0; rg < 4; ++rg) { bestv[i][rg] = -2.0f; besti[i][rg] = 0; }

    f32x4 acc0[4][4], acc1[4][4];
#pragma unroll
    for (int i = 0; i < 4; ++i)
#pragma unroll
        for (int j = 0; j < 4; ++j) {
            acc0[i][j] = (f32x4){0.f, 0.f, 0.f, 0.f};
            acc1[i][j] = (f32x4){0.f, 0.f, 0.f, 0.f};
        }

    auto STAGE = [&](int c, int buf) {
        const int tile = c >> 3;
        const int kk = (c & (CPT - 1)) * KCH;
        const int rowb = isA ? rbase : (cbase + tile * CB);
        const _Float16* g0 = src + (size_t)(rowb + (lane & 15)) * DIM + kk + (lane >> 4) * 8;
        _Float16* l0 = &smem[buf][w * 4096];
#pragma unroll
        for (int q = 0; q < 8; ++q)
            gload16(g0 + (size_t)q * 16 * DIM, l0 + q * 512);
    };

    STAGE(0, 0);
    asm volatile("s_waitcnt vmcnt(0)" ::: "memory");
    __builtin_amdgcn_s_barrier();

#pragma unroll 1
    for (int c = 0; c < NCHUNKS; ++c) {
        const int buf = c & 1;
        if (c + 1 < NCHUNKS) STAGE(c + 1, buf ^ 1);   // prefetch in flight over compute

        const _Float16* lAh = &smem[buf][0];
        const _Float16* lAl = &smem[buf][4096];
        const _Float16* lBh = &smem[buf][8192];
        const _Float16* lBl = &smem[buf][12288];

        f16x8 Ah[4], Al[4];
#pragma unroll
        for (int i = 0; i < 4; ++i) {
            const int fi = (wr * 4 + i) * 512 + lane * 8;
            Ah[i] = *(const f16x8*)(lAh + fi);
            Al[i] = *(const f16x8*)(lAl + fi);
        }
#pragma unroll
        for (int j = 0; j < 4; ++j) {
            const int fj = (wc * 4 + j) * 512 + lane * 8;
            const f16x8 Bh = *(const f16x8*)(lBh + fj);
            const f16x8 Bl = *(const f16x8*)(lBl + fj);
#pragma unroll
            for (int i = 0; i < 4; ++i) {
                acc0[i][j] = __builtin_amdgcn_mfma_f32_16x16x32_f16(Ah[i], Bh, acc0[i][j], 0, 0, 0);
                acc1[i][j] = __builtin_amdgcn_mfma_f32_16x16x32_f16(Ah[i], Bl, acc1[i][j], 0, 0, 0);
                acc1[i][j] = __builtin_amdgcn_mfma_f32_16x16x32_f16(Al[i], Bh, acc1[i][j], 0, 0, 0);
            }
        }

        if ((c & (CPT - 1)) == CPT - 1) {
            // tile finished: fused argmax epilogue (runs while prefetch in flight)
            const int cb = cbase + (c >> 3) * CB;
#pragma unroll
            for (int i = 0; i < 4; ++i) {
#pragma unroll
                for (int rg = 0; rg < 4; ++rg) {
                    float bv = -3e30f; int bix = 0;
#pragma unroll
                    for (int j = 0; j < 4; ++j) {
                        const float vv = acc0[i][j][rg] + acc1[i][j][rg] * (1.0f / 2048.0f);
                        const int ii = cb + wc * 64 + j * 16 + (lane & 15);
                        if (vv > bv) { bv = vv; bix = ii; }
                    }
#pragma unroll
                    for (int off = 1; off < 16; off <<= 1) {
                        const float ov = __shfl_xor(bv, off, 16);
                        const int oi = __shfl_xor(bix, off, 16);
                        if (ov > bv || (ov == bv && oi < bix)) { bv = ov; bix = oi; }
                    }
                    if (bv > bestv[i][rg]) { bestv[i][rg] = bv; besti[i][rg] = bix; }
                }
            }
#pragma unroll
            for (int i = 0; i < 4; ++i)
#pragma unroll
                for (int j = 0; j < 4; ++j) {
                    acc0[i][j] = (f32x4){0.f, 0.f, 0.f, 0.f};
                    acc1[i][j] = (f32x4){0.f, 0.f, 0.f, 0.f};
                }
        }

        asm volatile("s_waitcnt vmcnt(0)" ::: "memory");   // next-chunk stage landed
        __builtin_amdgcn_s_barrier();
    }

    // one private slot per (row, split, wc): no cross-wave race
    if ((lane & 15) == 0) {
#pragma unroll
        for (int i = 0; i < 4; ++i)
#pragma unroll
            for (int rg = 0; rg < 4; ++rg) {
                const int r = rbase + wr * 64 + i * 16 + (lane >> 4) * 4 + rg;
                cand_val[(size_t)r * NCAND + blockIdx.y * 2 + wc] = bestv[i][rg];
                cand_idx[(size_t)r * NCAND + blockIdx.y * 2 + wc] = besti[i][rg];
            }
    }
}

// ---------- merge splits + gather quantize + scatter embed_sum ----------
__global__ __launch_bounds__(256) void k_merge(
    const float* __restrict__ x, const float* __restrict__ embed,
    const float* __restrict__ cand_val, const int* __restrict__ cand_idx,
    const float* __restrict__ xnorm,
    float* __restrict__ quantize, float* __restrict__ ind_out,
    float* __restrict__ embed_sum, float* __restrict__ bins)
{
    const int w = threadIdx.x >> 6, lane = threadIdx.x & 63;
    const int r = blockIdx.x * 4 + w;
    float v = -3e30f; int ix = 0x7fffffff;
    if (lane < NCAND) {
        v = cand_val[(size_t)r * NCAND + lane];
        ix = cand_idx[(size_t)r * NCAND + lane];
    }
#pragma unroll
    for (int off = 1; off < 16; off <<= 1) {
        const float ov = __shfl_xor(v, off, 16);
        const int oi = __shfl_xor(ix, off, 16);
        if (ov > v || (ov == v && oi < ix)) { v = ov; ix = oi; }
    }
    ix = __shfl(ix, 0, 64);
    if (lane == 0) {
        ind_out[r] = (float)ix;
        atomicAdd(&bins[ix], 1.0f);
    }
    f32x4 e = *(const f32x4*)&embed[(size_t)ix * DIM + lane * 4];
    *(f32x4*)&quantize[(size_t)r * DIM + lane * 4] = e;
    f32x4 xv = *(const f32x4*)&x[(size_t)r * DIM + lane * 4];
    const float n = xnorm[r];
    atomicAdd(&embed_sum[(size_t)ix * DIM + lane * 4 + 0], xv[0] / n);
    atomicAdd(&embed_sum[(size_t)ix * DIM + lane * 4 + 1], xv[1] / n);
    atomicAdd(&embed_sum[(size_t)ix * DIM + lane * 4 + 2], xv[2] / n);
    atomicAdd(&embed_sum[(size_t)ix * DIM + lane * 4 + 3], xv[3] / n);
}

// ---------- EMA update (en recomputed inline) ----------
__global__ __launch_bounds__(256) void k_update(const float* __restrict__ embed,
    const float* __restrict__ embed_sum, const float* __restrict__ bins,
    float* __restrict__ embed_new, int K)
{
    const int w = threadIdx.x >> 6, lane = threadIdx.x & 63;
    const int k = blockIdx.x * 4 + w;
    if (k >= K) return;
    f32x4 e = *(const f32x4*)&embed[(size_t)k * DIM + lane * 4];
    float sse = waveReduceSum(e[0]*e[0] + e[1]*e[1] + e[2]*e[2] + e[3]*e[3]);
    const float ne = fmaxf(sqrtf(sse), 1e-12f);

    const float b = bins[k];
    const float bs = (b == 0.f) ? 1.f : b;
    f32x4 s = *(const f32x4*)&embed_sum[(size_t)k * DIM + lane * 4];
    f32x4 vv;
    vv[0] = s[0] / bs; vv[1] = s[1] / bs; vv[2] = s[2] / bs; vv[3] = s[3] / bs;
    float ssv = waveReduceSum(vv[0]*vv[0] + vv[1]*vv[1] + vv[2]*vv[2] + vv[3]*vv[3]);
    const float nv = fmaxf(sqrtf(ssv), 1e-12f);

    f32x4 o;
#pragma unroll
    for (int c = 0; c < 4; ++c) {
        const float norm_c = (b == 0.f) ? (e[c] / ne) : (vv[c] / nv);
        o[c] = 0.8f * e[c] + 0.2f * norm_c;
    }
    *(f32x4*)&embed_new[(size_t)k * DIM + lane * 4] = o;
}

extern "C" void kernel_launch(void* const* d_in, const int* in_sizes, int n_in,
                              void* d_out, int out_size, void* d_ws, size_t ws_size,
                              hipStream_t stream) {
    const float* x = (const float*)d_in[0];
    const float* embed = (const float*)d_in[1];
    const int N = in_sizes[0] / DIM;   // 16384
    const int K = in_sizes[1] / DIM;   // 8192

    float* quantize  = (float*)d_out;
    float* ind_out   = quantize + (size_t)N * DIM;
    float* embed_new = ind_out + N;

    char* ws = (char*)d_ws;
    _Float16* fnh = (_Float16*)ws;                               // [0, 8M)
    _Float16* fnl = (_Float16*)(ws + (size_t)N * DIM * 2);       // [8M, 16M)
    _Float16* enh = (_Float16*)(ws + (size_t)N * DIM * 4);       // [16M, 20M)
    _Float16* enl = (_Float16*)(ws + (size_t)N * DIM * 4 + (size_t)K * DIM * 2);
    char* p = ws + (size_t)N * DIM * 4 + (size_t)K * DIM * 4;    // 24M
    float* xnorm    = (float*)p;                 p += (size_t)N * 4;
    float* cand_val = (float*)p;                 p += (size_t)N * NCAND * 4;
    int*   cand_idx = (int*)p;
    // embed_sum/bins alias fnh/fnl (dead after k_gemm)
    float* embed_sum = (float*)ws;               // K*DIM floats = 8 MB
    float* bins      = embed_sum + (size_t)K * DIM;

    k_prep<<<(N + 3) / 4, 256, 0, stream>>>(x, fnh, fnl, xnorm, N);
    k_prep<<<(K + 3) / 4, 256, 0, stream>>>(embed, enh, enl, nullptr, K);

    dim3 grid(N / NROWS_TILE, SPLITS);
    k_gemm<<<grid, 256, 0, stream>>>(fnh, fnl, enh, enl, cand_val, cand_idx);

    hipMemsetAsync(embed_sum, 0, ((size_t)K * DIM + K) * sizeof(float), stream);

    k_merge<<<(N + 3) / 4, 256, 0, stream>>>(x, embed, cand_val, cand_idx, xnorm,
                                             quantize, ind_out, embed_sum, bins);
    k_update<<<(K + 3) / 4, 256, 0, stream>>>(embed, embed_sum, bins, embed_new, K);
}